// Round 28
// baseline (158.462 us; speedup 1.0000x reference)
//
#include <hip/hip_runtime.h>

#define N_NODES 100000
#define N_EDGES 1600000
#define DIM 64

#define NSLICE 8
#define SLICE_NODES ((N_NODES + NSLICE - 1) / NSLICE)     // 12500 nodes/slice

#define CAP 32                     // 32 x 4B = exactly one 128B line per node
#define OVF_CAP 65536
#define WSCALE 16384.0f            // 15-bit fixed-point weight quantization

// ---- legacy exact-CSR path constants (fallback) ----
#define SCAN_BLK 2048
#define NSCAN ((N_NODES + 1 + SCAN_BLK - 1) / SCAN_BLK)
#define SRT_CAP (N_EDGES + 4 * N_NODES)

typedef float fv4 __attribute__((ext_vector_type(4)));   // native vec for nt-store

__device__ __forceinline__ unsigned short f2bf(float f) {
    unsigned b = __float_as_uint(f);
    return (unsigned short)((b + 0x7FFFu + ((b >> 16) & 1u)) >> 16);  // RNE
}
__device__ __forceinline__ float bf2f(unsigned short u) {
    return __uint_as_float(((unsigned)u) << 16);
}

// ===========================================================================
// Path A: R25-exact (best: 152.5us) + nt hint on pull's srt reads
// ===========================================================================

__global__ void init_kernel(unsigned* __restrict__ cursor,
                            unsigned* __restrict__ ovf_cnt) {
    int i = blockIdx.x * blockDim.x + threadIdx.x;
    if (i < N_NODES + 8) cursor[i] = 0u;     // +8 pad for eighth-wave reads
    if (i == 0) *ovf_cnt = 0u;
}

// R25-exact scatter: NSLICE=8, all input streams nt, 4B packed entries.
// Measured optimum across NSLICE {4,8,16}, nt/cached, 8B/4B entries.
__global__ void scatter_fixed_kernel(const int* __restrict__ src,
                                     const int* __restrict__ dst,
                                     const float* __restrict__ w,
                                     unsigned* __restrict__ cursor,
                                     unsigned* __restrict__ srt,
                                     unsigned* __restrict__ ovf_cnt,
                                     uint4* __restrict__ ovf) {
    int slice = blockIdx.x & (NSLICE - 1);
    int chunk = blockIdx.x >> 3;
    int nchunks = gridDim.x >> 3;
    int lo = slice * SLICE_NODES;
    int hi = lo + SLICE_NODES; if (hi > N_NODES) hi = N_NODES;
    int per = (N_EDGES + nchunks - 1) / nchunks;
    int e0 = chunk * per;
    int e1 = e0 + per; if (e1 > N_EDGES) e1 = N_EDGES;
    for (int e = e0 + threadIdx.x; e < e1; e += blockDim.x) {
        int d = __builtin_nontemporal_load(&dst[e]);
        if (d >= lo && d < hi) {
            int s = __builtin_nontemporal_load(&src[e]);
            float ww = __builtin_nontemporal_load(&w[e]);
            unsigned pos = atomicAdd(&cursor[d], 1u);
            if (pos < CAP) {
                unsigned wq = (unsigned)(ww * WSCALE + 0.5f);   // 0..16384
                srt[(size_t)d * CAP + pos] = (unsigned)s | (wq << 17);
            } else {
                unsigned op = atomicAdd(ovf_cnt, 1u);
                if (op < OVF_CAP)
                    ovf[op] = make_uint4((unsigned)d, (unsigned)s,
                                         __float_as_uint(ww), 0u);
            }
        }
    }
}

// g = feat @ W, stored BF16 (unchanged from R16).
__global__ __launch_bounds__(256) void gemm_g_bf16_kernel(
        const float* __restrict__ feat, const float* __restrict__ W,
        unsigned short* __restrict__ g) {
    __shared__ float4 ft[64 * 16];   // 16 KB
    int tid = threadIdx.x, lane = tid & 63, wv = tid >> 6;

    float Wreg[DIM];
#pragma unroll
    for (int k = 0; k < DIM; ++k) Wreg[k] = W[k * DIM + lane];

    const float4* feat4 = (const float4*)feat;
    for (int tile = blockIdx.x; tile * 64 < N_NODES; tile += gridDim.x) {
        int base = tile * 64;
        int nrows = N_NODES - base; if (nrows > 64) nrows = 64;
        __syncthreads();
        for (int i = tid; i < 64 * 16; i += 256) {
            int r = i >> 4;
            ft[i] = (r < nrows) ? feat4[(size_t)(base + r) * 16 + (i & 15)]
                                : float4{0.f, 0.f, 0.f, 0.f};
        }
        __syncthreads();
        for (int r = wv; r < nrows; r += 4) {
            float acc = 0.f;
#pragma unroll
            for (int k4 = 0; k4 < 16; ++k4) {
                float4 f = ft[r * 16 + k4];   // uniform -> LDS broadcast
                acc = fmaf(f.x, Wreg[4 * k4 + 0], acc);
                acc = fmaf(f.y, Wreg[4 * k4 + 1], acc);
                acc = fmaf(f.z, Wreg[4 * k4 + 2], acc);
                acc = fmaf(f.w, Wreg[4 * k4 + 3], acc);
            }
            g[(size_t)(base + r) * DIM + lane] = f2bf(acc);
        }
    }
}

// Eighth-wave pull; single change vs R25: srt entries read with nt hint
// (read exactly once -> don't evict g's L2 working set).
__global__ __launch_bounds__(256) void pull_eighth_kernel(
        const unsigned short* __restrict__ g, const unsigned* __restrict__ srt,
        const unsigned* __restrict__ cursor, const float* __restrict__ bias,
        float* __restrict__ out) {
    int tid = threadIdx.x;
    int lane = tid & 63;
    int q = lane >> 3;             // node v0+q (0..7)
    int ln8 = lane & 7;            // dims 8*ln8 .. 8*ln8+7
    float bv0 = bias[8 * ln8 + 0], bv1 = bias[8 * ln8 + 1];
    float bv2 = bias[8 * ln8 + 2], bv3 = bias[8 * ln8 + 3];
    float bv4 = bias[8 * ln8 + 4], bv5 = bias[8 * ln8 + 5];
    float bv6 = bias[8 * ln8 + 6], bv7 = bias[8 * ln8 + 7];
    int gw = (int)((blockIdx.x * blockDim.x + tid) >> 6);
    int nw = (int)((gridDim.x * blockDim.x) >> 6);

    const uint4* g128 = (const uint4*)g;   // packed bf16x8 view (16B per 8 dims)
    const float inv = 1.0f / WSCALE;

    for (int v0 = 8 * gw; v0 < N_NODES; v0 += 8 * nw) {
        int vq = v0 + q;
        int myc = 0;
        if (vq < N_NODES) {
            myc = (int)cursor[vq];         // per-lane (group-broadcast) read
            myc = myc < CAP ? myc : CAP;
        }
        const unsigned* p = srt + (size_t)vq * CAP;

        float a0 = 0.f, a1 = 0.f, a2 = 0.f, a3 = 0.f;
        float a4 = 0.f, a5 = 0.f, a6 = 0.f, a7 = 0.f;
        for (int k = 0; k < myc; k += 4) {     // exec-masked divergence
#pragma unroll
            for (int j = 0; j < 4; ++j) {
                unsigned e = __builtin_nontemporal_load(&p[k + j]);
                unsigned s = (k + j < myc) ? (e & 0x1FFFFu) : 0u;
                float   ww = (k + j < myc)
                               ? (float)(e >> 17) * inv : 0.f;
                uint4 pk = g128[(size_t)s * (DIM / 8) + ln8];
                a0 = fmaf(__uint_as_float(pk.x << 16), ww, a0);
                a1 = fmaf(__uint_as_float(pk.x & 0xFFFF0000u), ww, a1);
                a2 = fmaf(__uint_as_float(pk.y << 16), ww, a2);
                a3 = fmaf(__uint_as_float(pk.y & 0xFFFF0000u), ww, a3);
                a4 = fmaf(__uint_as_float(pk.z << 16), ww, a4);
                a5 = fmaf(__uint_as_float(pk.z & 0xFFFF0000u), ww, a5);
                a6 = fmaf(__uint_as_float(pk.w << 16), ww, a6);
                a7 = fmaf(__uint_as_float(pk.w & 0xFFFF0000u), ww, a7);
            }
        }
        if (vq < N_NODES) {
            fv4 r0, r1;
            r0.x = a0 + bv0; r0.y = a1 + bv1; r0.z = a2 + bv2; r0.w = a3 + bv3;
            r1.x = a4 + bv4; r1.y = a5 + bv5; r1.z = a6 + bv6; r1.w = a7 + bv7;
            float* op = &out[(size_t)vq * DIM + 8 * ln8];
            __builtin_nontemporal_store(r0, (fv4*)op);
            __builtin_nontemporal_store(r1, (fv4*)(op + 4));
        }
    }
}

// Apply rare overflow edges (pos >= CAP) after pull wrote out.
__global__ void cleanup_ovf_kernel(const unsigned short* __restrict__ g,
                                   const uint4* __restrict__ ovf,
                                   const unsigned* __restrict__ ovf_cnt,
                                   float* __restrict__ out) {
    int lane = threadIdx.x & 63;
    int wv = (int)((blockIdx.x * blockDim.x + threadIdx.x) >> 6);
    int nwv = (int)((gridDim.x * blockDim.x) >> 6);
    unsigned nraw = *ovf_cnt;
    int n = (int)(nraw < (unsigned)OVF_CAP ? nraw : (unsigned)OVF_CAP);
    for (int i = wv; i < n; i += nwv) {
        uint4 t = ovf[i];
        atomicAdd(&out[(size_t)t.x * DIM + lane],
                  bf2f(g[(size_t)t.y * DIM + lane]) * __uint_as_float(t.z));
    }
}

// ===========================================================================
// Path B (fallback): R7 exact padded-CSR pipeline (fp32 g)
// ===========================================================================

__global__ void zero_u32(unsigned* __restrict__ p, int n) {
    int stride = gridDim.x * blockDim.x;
    for (int i = blockIdx.x * blockDim.x + threadIdx.x; i < n; i += stride)
        p[i] = 0u;
}

__global__ __launch_bounds__(256) void gemm_g_kernel(const float* __restrict__ feat,
                                                     const float* __restrict__ W,
                                                     float* __restrict__ g) {
    __shared__ float4 ft[64 * 16];
    int tid = threadIdx.x, lane = tid & 63, wv = tid >> 6;
    float Wreg[DIM];
#pragma unroll
    for (int k = 0; k < DIM; ++k) Wreg[k] = W[k * DIM + lane];
    const float4* feat4 = (const float4*)feat;
    for (int tile = blockIdx.x; tile * 64 < N_NODES; tile += gridDim.x) {
        int base = tile * 64;
        int nrows = N_NODES - base; if (nrows > 64) nrows = 64;
        __syncthreads();
        for (int i = tid; i < 64 * 16; i += 256) {
            int r = i >> 4;
            ft[i] = (r < nrows) ? feat4[(size_t)(base + r) * 16 + (i & 15)]
                                : float4{0.f, 0.f, 0.f, 0.f};
        }
        __syncthreads();
        for (int r = wv; r < nrows; r += 4) {
            float acc = 0.f;
#pragma unroll
            for (int k4 = 0; k4 < 16; ++k4) {
                float4 f = ft[r * 16 + k4];
                acc = fmaf(f.x, Wreg[4 * k4 + 0], acc);
                acc = fmaf(f.y, Wreg[4 * k4 + 1], acc);
                acc = fmaf(f.z, Wreg[4 * k4 + 2], acc);
                acc = fmaf(f.w, Wreg[4 * k4 + 3], acc);
            }
            g[(size_t)(base + r) * DIM + lane] = acc;
        }
    }
}

__global__ void hist_kernel(const int* __restrict__ dst, unsigned* __restrict__ cnt) {
    int slice = blockIdx.x & (NSLICE - 1);
    int chunk = blockIdx.x >> 3;
    int nchunks = gridDim.x >> 3;
    int lo = slice * SLICE_NODES;
    int hi = lo + SLICE_NODES; if (hi > N_NODES) hi = N_NODES;
    int per = (N_EDGES + nchunks - 1) / nchunks;
    int e0 = chunk * per;
    int e1 = e0 + per; if (e1 > N_EDGES) e1 = N_EDGES;
    for (int e = e0 + threadIdx.x; e < e1; e += blockDim.x) {
        int d = dst[e];
        if (d >= lo && d < hi) atomicAdd(&cnt[d], 1u);
    }
}

__global__ void scan1_kernel(const unsigned* __restrict__ cnt,
                             unsigned* __restrict__ off,
                             unsigned* __restrict__ partials) {
    __shared__ unsigned s[SCAN_BLK];
    int t = threadIdx.x;
    int base = blockIdx.x * SCAN_BLK;
    int i0 = base + t, i1 = base + t + 1024;
    unsigned c0 = (i0 < N_NODES) ? ((cnt[i0] + 3u) & ~3u) : 0u;
    unsigned c1 = (i1 < N_NODES) ? ((cnt[i1] + 3u) & ~3u) : 0u;
    s[t] = c0;
    s[t + 1024] = c1;
    __syncthreads();
    for (int o = 1; o < SCAN_BLK; o <<= 1) {
        unsigned a0 = s[t];
        unsigned a1 = s[t + 1024];
        unsigned b0 = (t >= o) ? s[t - o] : 0u;
        unsigned b1 = (t + 1024 >= o) ? s[t + 1024 - o] : 0u;
        __syncthreads();
        s[t] = a0 + b0;
        s[t + 1024] = a1 + b1;
        __syncthreads();
    }
    for (int i = t; i < SCAN_BLK; i += 1024) {
        int gg = base + i;
        if (gg <= N_NODES) off[gg] = (i == 0) ? 0u : s[i - 1];
    }
    if (t == 0) partials[blockIdx.x] = s[SCAN_BLK - 1];
}

__global__ void scan2_kernel(unsigned* __restrict__ partials) {
    int t = threadIdx.x;
    unsigned v = (t < NSCAN) ? partials[t] : 0u;
    unsigned orig = v;
    for (int o = 1; o < 64; o <<= 1) {
        unsigned n = __shfl_up(v, o, 64);
        if (t >= o) v += n;
    }
    if (t < NSCAN) partials[t] = v - orig;
}

__global__ void scan3_kernel(unsigned* __restrict__ off,
                             const unsigned* __restrict__ partials,
                             unsigned* __restrict__ cursor) {
    int i = blockIdx.x * blockDim.x + threadIdx.x;
    if (i <= N_NODES) {
        unsigned v = off[i] + partials[i / SCAN_BLK];
        off[i] = v;
        if (i < N_NODES) cursor[i] = v;
    }
}

__global__ void scatter_sort_kernel(const int* __restrict__ src,
                                    const int* __restrict__ dst,
                                    const float* __restrict__ w,
                                    unsigned* __restrict__ cursor,
                                    uint2* __restrict__ srt) {
    int slice = blockIdx.x & (NSLICE - 1);
    int chunk = blockIdx.x >> 3;
    int nchunks = gridDim.x >> 3;
    int lo = slice * SLICE_NODES;
    int hi = lo + SLICE_NODES; if (hi > N_NODES) hi = N_NODES;
    int per = (N_EDGES + nchunks - 1) / nchunks;
    int e0 = chunk * per;
    int e1 = e0 + per; if (e1 > N_EDGES) e1 = N_EDGES;
    for (int e = e0 + threadIdx.x; e < e1; e += blockDim.x) {
        int d = dst[e];
        if (d >= lo && d < hi) {
            unsigned pos = atomicAdd(&cursor[d], 1u);
            srt[pos] = make_uint2((unsigned)src[e], __float_as_uint(w[e]));
        }
    }
}

__global__ __launch_bounds__(256) void pull_scalar_kernel(
        const float* __restrict__ g, const uint2* __restrict__ srt,
        const unsigned* __restrict__ off, const float* __restrict__ bias,
        float* __restrict__ out) {
    int tid = threadIdx.x, lane = tid & 63;
    float bv = bias[lane];
    int gw = (int)((blockIdx.x * blockDim.x + tid) >> 6);
    int nw = (int)((gridDim.x * blockDim.x) >> 6);

    for (int v = gw; v < N_NODES; v += 2 * nw) {
        int vB = v + nw;
        int bA = (int)__builtin_amdgcn_readfirstlane((int)off[v]);
        int cA = (int)__builtin_amdgcn_readfirstlane((int)off[v + 1]) - bA;
        int bB = 0, cB = 0;
        if (vB < N_NODES) {
            bB = (int)__builtin_amdgcn_readfirstlane((int)off[vB]);
            cB = (int)__builtin_amdgcn_readfirstlane((int)off[vB + 1]) - bB;
        }
        float accA = 0.f, accB = 0.f;
        int kmax = cA > cB ? cA : cB;
        for (int k = 0; k < kmax; k += 4) {
            if (k < cA) {
                uint2 e0 = srt[bA + k + 0];
                uint2 e1 = srt[bA + k + 1];
                uint2 e2 = srt[bA + k + 2];
                uint2 e3 = srt[bA + k + 3];
                accA = fmaf(g[e0.x * DIM + lane], __uint_as_float(e0.y), accA);
                accA = fmaf(g[e1.x * DIM + lane], __uint_as_float(e1.y), accA);
                accA = fmaf(g[e2.x * DIM + lane], __uint_as_float(e2.y), accA);
                accA = fmaf(g[e3.x * DIM + lane], __uint_as_float(e3.y), accA);
            }
            if (k < cB) {
                uint2 e0 = srt[bB + k + 0];
                uint2 e1 = srt[bB + k + 1];
                uint2 e2 = srt[bB + k + 2];
                uint2 e3 = srt[bB + k + 3];
                accB = fmaf(g[e0.x * DIM + lane], __uint_as_float(e0.y), accB);
                accB = fmaf(g[e1.x * DIM + lane], __uint_as_float(e1.y), accB);
                accB = fmaf(g[e2.x * DIM + lane], __uint_as_float(e2.y), accB);
                accB = fmaf(g[e3.x * DIM + lane], __uint_as_float(e3.y), accB);
            }
        }
        out[(size_t)v * DIM + lane] = accA + bv;
        if (vB < N_NODES) out[(size_t)vB * DIM + lane] = accB + bv;
    }
}

// ===========================================================================
extern "C" void kernel_launch(void* const* d_in, const int* in_sizes, int n_in,
                              void* d_out, int out_size, void* d_ws, size_t ws_size,
                              hipStream_t stream) {
    const float* feat   = (const float*)d_in[0];
    const float* edge_w = (const float*)d_in[1];
    const int*   src    = (const int*)d_in[2];
    const int*   dst    = (const int*)d_in[3];
    const float* weight = (const float*)d_in[4];
    const float* bias   = (const float*)d_in[5];
    float* out = (float*)d_out;

    size_t gb_sz   = (size_t)N_NODES * DIM * 2;              // 12.8 MB (bf16)
    gb_sz = (gb_sz + 255) & ~(size_t)255;
    size_t srt_sz  = (size_t)N_NODES * CAP * 4;              // 12.8 MB (4B packed)
    size_t cur_sz  = (size_t)(N_NODES + 8) * 4;              // +8 pad
    cur_sz = (cur_sz + 63) & ~(size_t)63;
    size_t meta_sz = 64;
    size_t ovf_sz  = (size_t)OVF_CAP * 16;                   // 1 MB
    size_t neededA = gb_sz + srt_sz + cur_sz + meta_sz + ovf_sz;  // ~27 MB

    size_t g_sz    = (size_t)N_NODES * DIM * 4;
    size_t srtB_sz = (size_t)SRT_CAP * 8;

    if (ws_size >= neededA) {
        char* base = (char*)d_ws;
        unsigned short* g = (unsigned short*)base;
        unsigned* srt     = (unsigned*)(base + gb_sz);
        unsigned* cursor  = (unsigned*)(base + gb_sz + srt_sz);
        unsigned* ovf_cnt = (unsigned*)(base + gb_sz + srt_sz + cur_sz);
        uint4*    ovf     = (uint4*)(base + gb_sz + srt_sz + cur_sz + meta_sz);

        init_kernel<<<(N_NODES + 8 + 255) / 256, 256, 0, stream>>>(cursor, ovf_cnt);
        scatter_fixed_kernel<<<2048, 256, 0, stream>>>(src, dst, edge_w,
                                                       cursor, srt, ovf_cnt, ovf);
        gemm_g_bf16_kernel<<<1563, 256, 0, stream>>>(feat, weight, g);
        pull_eighth_kernel<<<1563, 256, 0, stream>>>(g, srt, cursor, bias, out);
        cleanup_ovf_kernel<<<64, 256, 0, stream>>>(g, ovf, ovf_cnt, out);
    } else {
        // R7 exact padded-CSR path (proven, fp32 g)
        float*    g        = (float*)d_ws;
        uint2*    srt      = (uint2*)((char*)d_ws + g_sz);
        unsigned* cnt      = (unsigned*)((char*)d_ws + g_sz + srtB_sz);
        unsigned* off      = cnt + N_NODES;
        unsigned* cursor   = off + N_NODES + 1;
        unsigned* partials = cursor + N_NODES;

        zero_u32<<<(N_NODES + 255) / 256, 256, 0, stream>>>(cnt, N_NODES);
        zero_u32<<<2048, 256, 0, stream>>>((unsigned*)srt, SRT_CAP * 2);
        hist_kernel<<<2048, 256, 0, stream>>>(dst, cnt);
        scan1_kernel<<<NSCAN, 1024, 0, stream>>>(cnt, off, partials);
        scan2_kernel<<<1, 64, 0, stream>>>(partials);
        scan3_kernel<<<(N_NODES + 256) / 256, 256, 0, stream>>>(off, partials, cursor);
        scatter_sort_kernel<<<2048, 256, 0, stream>>>(src, dst, edge_w, cursor, srt);
        gemm_g_kernel<<<1563, 256, 0, stream>>>(feat, weight, g);
        pull_scalar_kernel<<<2048, 256, 0, stream>>>(g, srt, off, bias, out);
    }
}

// Round 29
// 152.102 us; speedup vs baseline: 1.0418x; 1.0418x over previous
//
#include <hip/hip_runtime.h>

#define N_NODES 100000
#define N_EDGES 1600000
#define DIM 64

#define NSLICE 8
#define SLICE_NODES ((N_NODES + NSLICE - 1) / NSLICE)     // 12500 nodes/slice

#define CAP 32                     // 32 x 4B = exactly one 128B line per node
#define OVF_CAP 65536
#define WSCALE 16384.0f            // 15-bit fixed-point weight quantization

// ---- legacy exact-CSR path constants (fallback) ----
#define SCAN_BLK 2048
#define NSCAN ((N_NODES + 1 + SCAN_BLK - 1) / SCAN_BLK)
#define SRT_CAP (N_EDGES + 4 * N_NODES)

typedef float fv4 __attribute__((ext_vector_type(4)));   // native vec for nt-store

__device__ __forceinline__ unsigned short f2bf(float f) {
    unsigned b = __float_as_uint(f);
    return (unsigned short)((b + 0x7FFFu + ((b >> 16) & 1u)) >> 16);  // RNE
}
__device__ __forceinline__ float bf2f(unsigned short u) {
    return __uint_as_float(((unsigned)u) << 16);
}

// ===========================================================================
// Path A (R25-exact, measured best 152.5us):
//   init -> scatter (8-slice, nt streams, 4B packed) -> gemm bf16
//   -> eighth-wave pull (cached srt reads) -> ovf cleanup
// ===========================================================================

__global__ void init_kernel(unsigned* __restrict__ cursor,
                            unsigned* __restrict__ ovf_cnt) {
    int i = blockIdx.x * blockDim.x + threadIdx.x;
    if (i < N_NODES + 8) cursor[i] = 0u;     // +8 pad for eighth-wave reads
    if (i == 0) *ovf_cnt = 0u;
}

// Measured optimum across: NSLICE {4,8,16}, nt/cached per stream,
// 8B/4B entries, 1/4-edge batching, grids {2048,4000,4096}.
__global__ void scatter_fixed_kernel(const int* __restrict__ src,
                                     const int* __restrict__ dst,
                                     const float* __restrict__ w,
                                     unsigned* __restrict__ cursor,
                                     unsigned* __restrict__ srt,
                                     unsigned* __restrict__ ovf_cnt,
                                     uint4* __restrict__ ovf) {
    int slice = blockIdx.x & (NSLICE - 1);
    int chunk = blockIdx.x >> 3;
    int nchunks = gridDim.x >> 3;
    int lo = slice * SLICE_NODES;
    int hi = lo + SLICE_NODES; if (hi > N_NODES) hi = N_NODES;
    int per = (N_EDGES + nchunks - 1) / nchunks;
    int e0 = chunk * per;
    int e1 = e0 + per; if (e1 > N_EDGES) e1 = N_EDGES;
    for (int e = e0 + threadIdx.x; e < e1; e += blockDim.x) {
        int d = __builtin_nontemporal_load(&dst[e]);
        if (d >= lo && d < hi) {
            int s = __builtin_nontemporal_load(&src[e]);
            float ww = __builtin_nontemporal_load(&w[e]);
            unsigned pos = atomicAdd(&cursor[d], 1u);
            if (pos < CAP) {
                unsigned wq = (unsigned)(ww * WSCALE + 0.5f);   // 0..16384
                srt[(size_t)d * CAP + pos] = (unsigned)s | (wq << 17);
            } else {
                unsigned op = atomicAdd(ovf_cnt, 1u);
                if (op < OVF_CAP)
                    ovf[op] = make_uint4((unsigned)d, (unsigned)s,
                                         __float_as_uint(ww), 0u);
            }
        }
    }
}

// g = feat @ W, stored BF16.
__global__ __launch_bounds__(256) void gemm_g_bf16_kernel(
        const float* __restrict__ feat, const float* __restrict__ W,
        unsigned short* __restrict__ g) {
    __shared__ float4 ft[64 * 16];   // 16 KB
    int tid = threadIdx.x, lane = tid & 63, wv = tid >> 6;

    float Wreg[DIM];
#pragma unroll
    for (int k = 0; k < DIM; ++k) Wreg[k] = W[k * DIM + lane];

    const float4* feat4 = (const float4*)feat;
    for (int tile = blockIdx.x; tile * 64 < N_NODES; tile += gridDim.x) {
        int base = tile * 64;
        int nrows = N_NODES - base; if (nrows > 64) nrows = 64;
        __syncthreads();
        for (int i = tid; i < 64 * 16; i += 256) {
            int r = i >> 4;
            ft[i] = (r < nrows) ? feat4[(size_t)(base + r) * 16 + (i & 15)]
                                : float4{0.f, 0.f, 0.f, 0.f};
        }
        __syncthreads();
        for (int r = wv; r < nrows; r += 4) {
            float acc = 0.f;
#pragma unroll
            for (int k4 = 0; k4 < 16; ++k4) {
                float4 f = ft[r * 16 + k4];   // uniform -> LDS broadcast
                acc = fmaf(f.x, Wreg[4 * k4 + 0], acc);
                acc = fmaf(f.y, Wreg[4 * k4 + 1], acc);
                acc = fmaf(f.z, Wreg[4 * k4 + 2], acc);
                acc = fmaf(f.w, Wreg[4 * k4 + 3], acc);
            }
            g[(size_t)(base + r) * DIM + lane] = f2bf(acc);
        }
    }
}

// Eighth-wave pull: 8 adjacent nodes/wave, 1 packed-bf16x8 uint4 gather per
// edge-step serves 8 nodes; cached srt reads (each 128B row touched 4x).
__global__ __launch_bounds__(256) void pull_eighth_kernel(
        const unsigned short* __restrict__ g, const unsigned* __restrict__ srt,
        const unsigned* __restrict__ cursor, const float* __restrict__ bias,
        float* __restrict__ out) {
    int tid = threadIdx.x;
    int lane = tid & 63;
    int q = lane >> 3;             // node v0+q (0..7)
    int ln8 = lane & 7;            // dims 8*ln8 .. 8*ln8+7
    float bv0 = bias[8 * ln8 + 0], bv1 = bias[8 * ln8 + 1];
    float bv2 = bias[8 * ln8 + 2], bv3 = bias[8 * ln8 + 3];
    float bv4 = bias[8 * ln8 + 4], bv5 = bias[8 * ln8 + 5];
    float bv6 = bias[8 * ln8 + 6], bv7 = bias[8 * ln8 + 7];
    int gw = (int)((blockIdx.x * blockDim.x + tid) >> 6);
    int nw = (int)((gridDim.x * blockDim.x) >> 6);

    const uint4* g128 = (const uint4*)g;   // packed bf16x8 view (16B per 8 dims)
    const float inv = 1.0f / WSCALE;

    for (int v0 = 8 * gw; v0 < N_NODES; v0 += 8 * nw) {
        int vq = v0 + q;
        int myc = 0;
        if (vq < N_NODES) {
            myc = (int)cursor[vq];         // per-lane (group-broadcast) read
            myc = myc < CAP ? myc : CAP;
        }
        const unsigned* p = srt + (size_t)vq * CAP;

        float a0 = 0.f, a1 = 0.f, a2 = 0.f, a3 = 0.f;
        float a4 = 0.f, a5 = 0.f, a6 = 0.f, a7 = 0.f;
        for (int k = 0; k < myc; k += 4) {     // exec-masked divergence
#pragma unroll
            for (int j = 0; j < 4; ++j) {
                unsigned e = p[k + j];                     // in-bounds (CAP slots)
                unsigned s = (k + j < myc) ? (e & 0x1FFFFu) : 0u;
                float   ww = (k + j < myc)
                               ? (float)(e >> 17) * inv : 0.f;
                uint4 pk = g128[(size_t)s * (DIM / 8) + ln8];
                a0 = fmaf(__uint_as_float(pk.x << 16), ww, a0);
                a1 = fmaf(__uint_as_float(pk.x & 0xFFFF0000u), ww, a1);
                a2 = fmaf(__uint_as_float(pk.y << 16), ww, a2);
                a3 = fmaf(__uint_as_float(pk.y & 0xFFFF0000u), ww, a3);
                a4 = fmaf(__uint_as_float(pk.z << 16), ww, a4);
                a5 = fmaf(__uint_as_float(pk.z & 0xFFFF0000u), ww, a5);
                a6 = fmaf(__uint_as_float(pk.w << 16), ww, a6);
                a7 = fmaf(__uint_as_float(pk.w & 0xFFFF0000u), ww, a7);
            }
        }
        if (vq < N_NODES) {
            fv4 r0, r1;
            r0.x = a0 + bv0; r0.y = a1 + bv1; r0.z = a2 + bv2; r0.w = a3 + bv3;
            r1.x = a4 + bv4; r1.y = a5 + bv5; r1.z = a6 + bv6; r1.w = a7 + bv7;
            float* op = &out[(size_t)vq * DIM + 8 * ln8];
            __builtin_nontemporal_store(r0, (fv4*)op);
            __builtin_nontemporal_store(r1, (fv4*)(op + 4));
        }
    }
}

// Apply rare overflow edges (pos >= CAP) after pull wrote out.
__global__ void cleanup_ovf_kernel(const unsigned short* __restrict__ g,
                                   const uint4* __restrict__ ovf,
                                   const unsigned* __restrict__ ovf_cnt,
                                   float* __restrict__ out) {
    int lane = threadIdx.x & 63;
    int wv = (int)((blockIdx.x * blockDim.x + threadIdx.x) >> 6);
    int nwv = (int)((gridDim.x * blockDim.x) >> 6);
    unsigned nraw = *ovf_cnt;
    int n = (int)(nraw < (unsigned)OVF_CAP ? nraw : (unsigned)OVF_CAP);
    for (int i = wv; i < n; i += nwv) {
        uint4 t = ovf[i];
        atomicAdd(&out[(size_t)t.x * DIM + lane],
                  bf2f(g[(size_t)t.y * DIM + lane]) * __uint_as_float(t.z));
    }
}

// ===========================================================================
// Path B (fallback): R7 exact padded-CSR pipeline (fp32 g)
// ===========================================================================

__global__ void zero_u32(unsigned* __restrict__ p, int n) {
    int stride = gridDim.x * blockDim.x;
    for (int i = blockIdx.x * blockDim.x + threadIdx.x; i < n; i += stride)
        p[i] = 0u;
}

__global__ __launch_bounds__(256) void gemm_g_kernel(const float* __restrict__ feat,
                                                     const float* __restrict__ W,
                                                     float* __restrict__ g) {
    __shared__ float4 ft[64 * 16];
    int tid = threadIdx.x, lane = tid & 63, wv = tid >> 6;
    float Wreg[DIM];
#pragma unroll
    for (int k = 0; k < DIM; ++k) Wreg[k] = W[k * DIM + lane];
    const float4* feat4 = (const float4*)feat;
    for (int tile = blockIdx.x; tile * 64 < N_NODES; tile += gridDim.x) {
        int base = tile * 64;
        int nrows = N_NODES - base; if (nrows > 64) nrows = 64;
        __syncthreads();
        for (int i = tid; i < 64 * 16; i += 256) {
            int r = i >> 4;
            ft[i] = (r < nrows) ? feat4[(size_t)(base + r) * 16 + (i & 15)]
                                : float4{0.f, 0.f, 0.f, 0.f};
        }
        __syncthreads();
        for (int r = wv; r < nrows; r += 4) {
            float acc = 0.f;
#pragma unroll
            for (int k4 = 0; k4 < 16; ++k4) {
                float4 f = ft[r * 16 + k4];
                acc = fmaf(f.x, Wreg[4 * k4 + 0], acc);
                acc = fmaf(f.y, Wreg[4 * k4 + 1], acc);
                acc = fmaf(f.z, Wreg[4 * k4 + 2], acc);
                acc = fmaf(f.w, Wreg[4 * k4 + 3], acc);
            }
            g[(size_t)(base + r) * DIM + lane] = acc;
        }
    }
}

__global__ void hist_kernel(const int* __restrict__ dst, unsigned* __restrict__ cnt) {
    int slice = blockIdx.x & (NSLICE - 1);
    int chunk = blockIdx.x >> 3;
    int nchunks = gridDim.x >> 3;
    int lo = slice * SLICE_NODES;
    int hi = lo + SLICE_NODES; if (hi > N_NODES) hi = N_NODES;
    int per = (N_EDGES + nchunks - 1) / nchunks;
    int e0 = chunk * per;
    int e1 = e0 + per; if (e1 > N_EDGES) e1 = N_EDGES;
    for (int e = e0 + threadIdx.x; e < e1; e += blockDim.x) {
        int d = dst[e];
        if (d >= lo && d < hi) atomicAdd(&cnt[d], 1u);
    }
}

__global__ void scan1_kernel(const unsigned* __restrict__ cnt,
                             unsigned* __restrict__ off,
                             unsigned* __restrict__ partials) {
    __shared__ unsigned s[SCAN_BLK];
    int t = threadIdx.x;
    int base = blockIdx.x * SCAN_BLK;
    int i0 = base + t, i1 = base + t + 1024;
    unsigned c0 = (i0 < N_NODES) ? ((cnt[i0] + 3u) & ~3u) : 0u;
    unsigned c1 = (i1 < N_NODES) ? ((cnt[i1] + 3u) & ~3u) : 0u;
    s[t] = c0;
    s[t + 1024] = c1;
    __syncthreads();
    for (int o = 1; o < SCAN_BLK; o <<= 1) {
        unsigned a0 = s[t];
        unsigned a1 = s[t + 1024];
        unsigned b0 = (t >= o) ? s[t - o] : 0u;
        unsigned b1 = (t + 1024 >= o) ? s[t + 1024 - o] : 0u;
        __syncthreads();
        s[t] = a0 + b0;
        s[t + 1024] = a1 + b1;
        __syncthreads();
    }
    for (int i = t; i < SCAN_BLK; i += 1024) {
        int gg = base + i;
        if (gg <= N_NODES) off[gg] = (i == 0) ? 0u : s[i - 1];
    }
    if (t == 0) partials[blockIdx.x] = s[SCAN_BLK - 1];
}

__global__ void scan2_kernel(unsigned* __restrict__ partials) {
    int t = threadIdx.x;
    unsigned v = (t < NSCAN) ? partials[t] : 0u;
    unsigned orig = v;
    for (int o = 1; o < 64; o <<= 1) {
        unsigned n = __shfl_up(v, o, 64);
        if (t >= o) v += n;
    }
    if (t < NSCAN) partials[t] = v - orig;
}

__global__ void scan3_kernel(unsigned* __restrict__ off,
                             const unsigned* __restrict__ partials,
                             unsigned* __restrict__ cursor) {
    int i = blockIdx.x * blockDim.x + threadIdx.x;
    if (i <= N_NODES) {
        unsigned v = off[i] + partials[i / SCAN_BLK];
        off[i] = v;
        if (i < N_NODES) cursor[i] = v;
    }
}

__global__ void scatter_sort_kernel(const int* __restrict__ src,
                                    const int* __restrict__ dst,
                                    const float* __restrict__ w,
                                    unsigned* __restrict__ cursor,
                                    uint2* __restrict__ srt) {
    int slice = blockIdx.x & (NSLICE - 1);
    int chunk = blockIdx.x >> 3;
    int nchunks = gridDim.x >> 3;
    int lo = slice * SLICE_NODES;
    int hi = lo + SLICE_NODES; if (hi > N_NODES) hi = N_NODES;
    int per = (N_EDGES + nchunks - 1) / nchunks;
    int e0 = chunk * per;
    int e1 = e0 + per; if (e1 > N_EDGES) e1 = N_EDGES;
    for (int e = e0 + threadIdx.x; e < e1; e += blockDim.x) {
        int d = dst[e];
        if (d >= lo && d < hi) {
            unsigned pos = atomicAdd(&cursor[d], 1u);
            srt[pos] = make_uint2((unsigned)src[e], __float_as_uint(w[e]));
        }
    }
}

__global__ __launch_bounds__(256) void pull_scalar_kernel(
        const float* __restrict__ g, const uint2* __restrict__ srt,
        const unsigned* __restrict__ off, const float* __restrict__ bias,
        float* __restrict__ out) {
    int tid = threadIdx.x, lane = tid & 63;
    float bv = bias[lane];
    int gw = (int)((blockIdx.x * blockDim.x + tid) >> 6);
    int nw = (int)((gridDim.x * blockDim.x) >> 6);

    for (int v = gw; v < N_NODES; v += 2 * nw) {
        int vB = v + nw;
        int bA = (int)__builtin_amdgcn_readfirstlane((int)off[v]);
        int cA = (int)__builtin_amdgcn_readfirstlane((int)off[v + 1]) - bA;
        int bB = 0, cB = 0;
        if (vB < N_NODES) {
            bB = (int)__builtin_amdgcn_readfirstlane((int)off[vB]);
            cB = (int)__builtin_amdgcn_readfirstlane((int)off[vB + 1]) - bB;
        }
        float accA = 0.f, accB = 0.f;
        int kmax = cA > cB ? cA : cB;
        for (int k = 0; k < kmax; k += 4) {
            if (k < cA) {
                uint2 e0 = srt[bA + k + 0];
                uint2 e1 = srt[bA + k + 1];
                uint2 e2 = srt[bA + k + 2];
                uint2 e3 = srt[bA + k + 3];
                accA = fmaf(g[e0.x * DIM + lane], __uint_as_float(e0.y), accA);
                accA = fmaf(g[e1.x * DIM + lane], __uint_as_float(e1.y), accA);
                accA = fmaf(g[e2.x * DIM + lane], __uint_as_float(e2.y), accA);
                accA = fmaf(g[e3.x * DIM + lane], __uint_as_float(e3.y), accA);
            }
            if (k < cB) {
                uint2 e0 = srt[bB + k + 0];
                uint2 e1 = srt[bB + k + 1];
                uint2 e2 = srt[bB + k + 2];
                uint2 e3 = srt[bB + k + 3];
                accB = fmaf(g[e0.x * DIM + lane], __uint_as_float(e0.y), accB);
                accB = fmaf(g[e1.x * DIM + lane], __uint_as_float(e1.y), accB);
                accB = fmaf(g[e2.x * DIM + lane], __uint_as_float(e2.y), accB);
                accB = fmaf(g[e3.x * DIM + lane], __uint_as_float(e3.y), accB);
            }
        }
        out[(size_t)v * DIM + lane] = accA + bv;
        if (vB < N_NODES) out[(size_t)vB * DIM + lane] = accB + bv;
    }
}

// ===========================================================================
extern "C" void kernel_launch(void* const* d_in, const int* in_sizes, int n_in,
                              void* d_out, int out_size, void* d_ws, size_t ws_size,
                              hipStream_t stream) {
    const float* feat   = (const float*)d_in[0];
    const float* edge_w = (const float*)d_in[1];
    const int*   src    = (const int*)d_in[2];
    const int*   dst    = (const int*)d_in[3];
    const float* weight = (const float*)d_in[4];
    const float* bias   = (const float*)d_in[5];
    float* out = (float*)d_out;

    size_t gb_sz   = (size_t)N_NODES * DIM * 2;              // 12.8 MB (bf16)
    gb_sz = (gb_sz + 255) & ~(size_t)255;
    size_t srt_sz  = (size_t)N_NODES * CAP * 4;              // 12.8 MB (4B packed)
    size_t cur_sz  = (size_t)(N_NODES + 8) * 4;              // +8 pad
    cur_sz = (cur_sz + 63) & ~(size_t)63;
    size_t meta_sz = 64;
    size_t ovf_sz  = (size_t)OVF_CAP * 16;                   // 1 MB
    size_t neededA = gb_sz + srt_sz + cur_sz + meta_sz + ovf_sz;  // ~27 MB

    size_t g_sz    = (size_t)N_NODES * DIM * 4;
    size_t srtB_sz = (size_t)SRT_CAP * 8;

    if (ws_size >= neededA) {
        char* base = (char*)d_ws;
        unsigned short* g = (unsigned short*)base;
        unsigned* srt     = (unsigned*)(base + gb_sz);
        unsigned* cursor  = (unsigned*)(base + gb_sz + srt_sz);
        unsigned* ovf_cnt = (unsigned*)(base + gb_sz + srt_sz + cur_sz);
        uint4*    ovf     = (uint4*)(base + gb_sz + srt_sz + cur_sz + meta_sz);

        init_kernel<<<(N_NODES + 8 + 255) / 256, 256, 0, stream>>>(cursor, ovf_cnt);
        scatter_fixed_kernel<<<2048, 256, 0, stream>>>(src, dst, edge_w,
                                                       cursor, srt, ovf_cnt, ovf);
        gemm_g_bf16_kernel<<<1563, 256, 0, stream>>>(feat, weight, g);
        pull_eighth_kernel<<<1563, 256, 0, stream>>>(g, srt, cursor, bias, out);
        cleanup_ovf_kernel<<<64, 256, 0, stream>>>(g, ovf, ovf_cnt, out);
    } else {
        // R7 exact padded-CSR path (proven, fp32 g)
        float*    g        = (float*)d_ws;
        uint2*    srt      = (uint2*)((char*)d_ws + g_sz);
        unsigned* cnt      = (unsigned*)((char*)d_ws + g_sz + srtB_sz);
        unsigned* off      = cnt + N_NODES;
        unsigned* cursor   = off + N_NODES + 1;
        unsigned* partials = cursor + N_NODES;

        zero_u32<<<(N_NODES + 255) / 256, 256, 0, stream>>>(cnt, N_NODES);
        zero_u32<<<2048, 256, 0, stream>>>((unsigned*)srt, SRT_CAP * 2);
        hist_kernel<<<2048, 256, 0, stream>>>(dst, cnt);
        scan1_kernel<<<NSCAN, 1024, 0, stream>>>(cnt, off, partials);
        scan2_kernel<<<1, 64, 0, stream>>>(partials);
        scan3_kernel<<<(N_NODES + 256) / 256, 256, 0, stream>>>(off, partials, cursor);
        scatter_sort_kernel<<<2048, 256, 0, stream>>>(src, dst, edge_w, cursor, srt);
        gemm_g_kernel<<<1563, 256, 0, stream>>>(feat, weight, g);
        pull_scalar_kernel<<<2048, 256, 0, stream>>>(g, srt, off, bias, out);
    }
}